// Round 3
// baseline (1920.220 us; speedup 1.0000x reference)
//
#include <hip/hip_runtime.h>
#include <math.h>

#define BB 4
#define LL 2048
#define HH 8
#define EE 64
#define TM 64
#define TN 64
#define SH 72   // fp16 LDS row stride: 36 dwords -> 4-bank offset per row

typedef _Float16 half4v __attribute__((ext_vector_type(4)));
typedef _Float16 half8v __attribute__((ext_vector_type(8)));
typedef float floatx4 __attribute__((ext_vector_type(4)));

static constexpr float SCALE = 0.125f;                    // 1/sqrt(64)
static constexpr float LN3 = 1.0986122886681098f;
static constexpr float INV_SQRT_2PI = 0.3989422804014327f;
static constexpr size_t NMAT = (size_t)BB * HH * LL * LL;
static constexpr size_t SERIES_BASE = (size_t)BB * LL * HH * EE;
static constexpr size_t PRIOR_BASE = SERIES_BASE + NMAT;
static constexpr size_t SIG_BASE = PRIOR_BASE + NMAT;

// ============================================================================
// Kernel A: pure streaming writes — prior (full), sig (full), series zero
// region. Barrier-free, 8 blocks/CU, NT stores (never re-read).
// ============================================================================
__global__ __launch_bounds__(256, 8)
void prior_sig_fill(const float* __restrict__ sgg, float* __restrict__ out) {
  const int lane = threadIdx.x & 63;
  const int wv = (blockIdx.x << 2) | (threadIdx.x >> 6);   // global wave id
  const int nw = gridDim.x << 2;
  const int totalRows = BB * HH * LL;
  for (int row = wv; row < totalRows; row += nw) {
    const int bh = row >> 11;          // row / LL
    const int i = row & (LL - 1);
    const int b = bh >> 3, h = bh & 7;
    float sg = sgg[((size_t)b * LL + i) * HH + h];
    float sd = 1.0f / (1.0f + __expf(-5.0f * sg)) + 1e-5f;
    float sv = expm1f(sd * LN3);       // 3^sd - 1, cancellation-safe
    float iv = INV_SQRT_2PI / sv;
    float c2 = 0.5f / (sv * sv);
    const size_t roff = ((size_t)bh * LL + i) * LL;
    const floatx4 s4 = {sv, sv, sv, sv};
    const float fi = (float)i;
#pragma unroll
    for (int it = 0; it < 8; ++it) {
      int j = (it << 8) + (lane << 2);           // 64 lanes x float4 = 256 cols
      float d0 = fi - (float)j;
      float d1 = d0 - 1.0f, d2 = d0 - 2.0f, d3 = d0 - 3.0f;
      floatx4 pr;
      pr.x = iv * __expf(-d0 * d0 * c2);
      pr.y = iv * __expf(-d1 * d1 * c2);
      pr.z = iv * __expf(-d2 * d2 * c2);
      pr.w = iv * __expf(-d3 * d3 * c2);
      __builtin_nontemporal_store(pr, (floatx4*)&out[PRIOR_BASE + roff + j]);
      __builtin_nontemporal_store(s4, (floatx4*)&out[SIG_BASE + roff + j]);
    }
    // series zero region: j in [ (i/64 + 1)*64, LL )
    const int jz = ((i >> 6) + 1) << 6;
    const floatx4 z = {0.f, 0.f, 0.f, 0.f};
    for (int j = jz + (lane << 2); j < LL; j += 256) {
      __builtin_nontemporal_store(z, (floatx4*)&out[SERIES_BASE + roff + j]);
    }
  }
}

// ============================================================================
// Kernel B: single-pass attention. QK^T computed ONCE; unnormalized exp
// stored to series + accumulated into row-sums and unnormalized PV; epilogue
// scales O in-register and rescales the causal series region in place.
// 2 barriers per j-tile (Ph is wave-local). 4 blocks/CU.
// ============================================================================
__global__ __launch_bounds__(256, 4)
void anomaly_attn(const float* __restrict__ qg,
                  const float* __restrict__ kg,
                  const float* __restrict__ vg,
                  float* __restrict__ out) {
  __shared__ __attribute__((aligned(16))) _Float16 Qh[TM * SH];
  __shared__ __attribute__((aligned(16))) _Float16 Kh[TN * SH];
  __shared__ __attribute__((aligned(16))) _Float16 Vt[EE * SH];  // transposed: [e][j]
  __shared__ __attribute__((aligned(16))) _Float16 Ph[TM * SH];
  __shared__ float s_linv[TM];

  const int t = threadIdx.x;
  const int lane = t & 63;
  const int w = t >> 6;          // wave id 0..3 -> rows w*16..w*16+15
  const int quad = lane >> 4;    // 0..3
  const int l15 = lane & 15;
  const int bh = blockIdx.y;
  const int b = bh >> 3, h = bh & 7;
  const int rt = blockIdx.x;     // one row tile per block
  const int i0 = rt * TM;
  const int nt = rt + 1;         // causal j-tiles
  const float4* q4 = (const float4*)qg;
  const float4* k4 = (const float4*)kg;
  const float4* v4 = (const float4*)vg;

  // ---- stage Q (fp32 -> fp16 LDS, row-major) ----
#pragma unroll
  for (int it = 0; it < 4; ++it) {
    int idx = t + 256 * it;
    int r = idx >> 4, c = idx & 15;
    float4 qv = q4[(((size_t)b * LL + i0 + r) * HH + h) * 16 + c];
    half4v hq = {(_Float16)qv.x, (_Float16)qv.y, (_Float16)qv.z, (_Float16)qv.w};
    *(half4v*)&Qh[r * SH + c * 4] = hq;
  }

  float lsum[4] = {0.f, 0.f, 0.f, 0.f};
  floatx4 Oacc[4] = {{0.f, 0.f, 0.f, 0.f}, {0.f, 0.f, 0.f, 0.f},
                     {0.f, 0.f, 0.f, 0.f}, {0.f, 0.f, 0.f, 0.f}};

  for (int jt = 0; jt < nt; ++jt) {
    const int j0 = jt * TN;
    __syncthreads();             // prev tile's Kh/Vt readers done (covers Qh 1st iter)
    // ---- stage K ----
#pragma unroll
    for (int it = 0; it < 4; ++it) {
      int idx = t + 256 * it;
      int r = idx >> 4, c = idx & 15;
      float4 kv = k4[(((size_t)b * LL + j0 + r) * HH + h) * 16 + c];
      half4v hk = {(_Float16)kv.x, (_Float16)kv.y, (_Float16)kv.z, (_Float16)kv.w};
      *(half4v*)&Kh[r * SH + c * 4] = hk;
    }
    // ---- stage V transposed: thread (tx=e-group, ty=j-group), 4x4 micro-transpose
    {
      const int tx = t & 15, ty = t >> 4;
      float4 vv[4];
#pragma unroll
      for (int rr = 0; rr < 4; ++rr)
        vv[rr] = v4[(((size_t)b * LL + j0 + ty * 4 + rr) * HH + h) * 16 + tx];
#pragma unroll
      for (int c = 0; c < 4; ++c) {
        float e0 = c == 0 ? vv[0].x : c == 1 ? vv[0].y : c == 2 ? vv[0].z : vv[0].w;
        float e1 = c == 0 ? vv[1].x : c == 1 ? vv[1].y : c == 2 ? vv[1].z : vv[1].w;
        float e2 = c == 0 ? vv[2].x : c == 1 ? vv[2].y : c == 2 ? vv[2].z : vv[2].w;
        float e3 = c == 0 ? vv[3].x : c == 1 ? vv[3].y : c == 2 ? vv[3].z : vv[3].w;
        half4v hv = {(_Float16)e0, (_Float16)e1, (_Float16)e2, (_Float16)e3};
        *(half4v*)&Vt[(tx * 4 + c) * SH + ty * 4] = hv;
      }
    }
    __syncthreads();             // staging visible to all waves

    // ---- QK^T MFMA ----
    floatx4 acc[4] = {{0.f, 0.f, 0.f, 0.f}, {0.f, 0.f, 0.f, 0.f},
                      {0.f, 0.f, 0.f, 0.f}, {0.f, 0.f, 0.f, 0.f}};
#pragma unroll
    for (int ks = 0; ks < 2; ++ks) {
      half8v a = *(half8v*)&Qh[(w * 16 + l15) * SH + ks * 32 + quad * 8];
#pragma unroll
      for (int f = 0; f < 4; ++f) {
        half8v bf = *(half8v*)&Kh[(f * 16 + l15) * SH + ks * 32 + quad * 8];
        acc[f] = __builtin_amdgcn_mfma_f32_16x16x32_f16(a, bf, acc[f], 0, 0, 0);
      }
    }
    // ---- P = exp(scale*s) UNNORMALIZED; accumulate lsum; Ph (wave-local rows) ----
#pragma unroll
    for (int f = 0; f < 4; ++f) {
      int j = j0 + f * 16 + l15;          // C col = lane&15
#pragma unroll
      for (int r = 0; r < 4; ++r) {
        int i = i0 + w * 16 + quad * 4 + r;   // C row = quad*4+reg
        float p = (j <= i) ? __expf(acc[f][r] * SCALE) : 0.f;
        lsum[r] += p;
        Ph[(w * 16 + quad * 4 + r) * SH + f * 16 + l15] = (_Float16)p;
      }
    }
    // ---- series store (unnormalized), wave-local Ph rows -> NO barrier ----
    // wave w owns rows w*16..w*16+15; coalesced: 8 lanes span one row (32B each)
#pragma unroll
    for (int rnd = 0; rnd < 2; ++rnd) {
      int row = w * 16 + rnd * 8 + (lane >> 3);
      int c8 = lane & 7;
      half8v p = *(half8v*)&Ph[row * SH + c8 * 8];
      floatx4 lo = {(float)p[0], (float)p[1], (float)p[2], (float)p[3]};
      floatx4 hi = {(float)p[4], (float)p[5], (float)p[6], (float)p[7]};
      size_t off = SERIES_BASE + ((size_t)bh * LL + i0 + row) * LL + j0 + c8 * 8;
      *(floatx4*)&out[off] = lo;          // plain: keep L2/LLC-resident for rescale
      *(floatx4*)&out[off + 4] = hi;
    }
    // ---- PV MFMA (Ph rows wave-local, Vt from this tile's staging) ----
#pragma unroll
    for (int ks = 0; ks < 2; ++ks) {
      half8v a = *(half8v*)&Ph[(w * 16 + l15) * SH + ks * 32 + quad * 8];
#pragma unroll
      for (int f = 0; f < 4; ++f) {
        half8v bv = *(half8v*)&Vt[(f * 16 + l15) * SH + ks * 32 + quad * 8];
        Oacc[f] = __builtin_amdgcn_mfma_f32_16x16x32_f16(a, bv, Oacc[f], 0, 0, 0);
      }
    }
  }

  // ---- row-sum reduce across l15 lanes (j covered 16-wide per quad) ----
#pragma unroll
  for (int r = 0; r < 4; ++r) {
    lsum[r] += __shfl_xor(lsum[r], 1);
    lsum[r] += __shfl_xor(lsum[r], 2);
    lsum[r] += __shfl_xor(lsum[r], 4);
    lsum[r] += __shfl_xor(lsum[r], 8);
  }
  float linv[4];
#pragma unroll
  for (int r = 0; r < 4; ++r) linv[r] = 1.0f / lsum[r];

  // ---- V output, scaled by linv ----
#pragma unroll
  for (int f = 0; f < 4; ++f) {
#pragma unroll
    for (int r = 0; r < 4; ++r) {
      int i = i0 + w * 16 + quad * 4 + r;
      out[(((size_t)b * LL + i) * HH + h) * EE + f * 16 + l15] = Oacc[f][r] * linv[r];
    }
  }

  // ---- stash per-row linv, then cooperative series rescale (in-place) ----
  if (l15 == 0) {
#pragma unroll
    for (int r = 0; r < 4; ++r) s_linv[w * 16 + quad * 4 + r] = linv[r];
  }
  __syncthreads();   // linv visible + all series stores drained (vmcnt(0))

  const int ncol4 = nt * 16;       // float4s per causal row
  const int rsub = t >> 6;         // 4 rows in flight, 64 lanes per row
  const int cl = t & 63;
  for (int rr = 0; rr < 16; ++rr) {
    int row = rr * 4 + rsub;
    float li = s_linv[row];
    size_t base = SERIES_BASE + ((size_t)bh * LL + i0 + row) * LL;
    for (int c = cl; c < ncol4; c += 64) {
      floatx4 v = *(const floatx4*)&out[base + c * 4];
      v *= li;
      __builtin_nontemporal_store(v, (floatx4*)&out[base + c * 4]);
    }
  }
}

extern "C" void kernel_launch(void* const* d_in, const int* in_sizes, int n_in,
                              void* d_out, int out_size, void* d_ws, size_t ws_size,
                              hipStream_t stream) {
  const float* q = (const float*)d_in[0];
  const float* k = (const float*)d_in[1];
  const float* v = (const float*)d_in[2];
  const float* sg = (const float*)d_in[3];
  float* out = (float*)d_out;
  // B: single-pass attention — one row tile per block, 4 blocks/CU
  dim3 grid(LL / TM, BB * HH);  // 32 x 32 = 1024 blocks, all co-resident
  anomaly_attn<<<grid, 256, 0, stream>>>(q, k, v, out);
  // A: streaming prior/sig/series-zeros — barrier-free, NT
  prior_sig_fill<<<dim3(2048), 256, 0, stream>>>(sg, out);
}

// Round 4
// 1768.868 us; speedup vs baseline: 1.0856x; 1.0856x over previous
//
#include <hip/hip_runtime.h>
#include <math.h>

#define BB 4
#define LL 2048
#define HH 8
#define EE 64
#define TM 64
#define TN 128
#define SH 72    // Q/K LDS fp16 row stride (64-elem rows)
#define SH2 136  // Ph/Vt LDS fp16 row stride (128-elem rows); 272B = 17*16 aligned

typedef _Float16 half4v __attribute__((ext_vector_type(4)));
typedef _Float16 half8v __attribute__((ext_vector_type(8)));
typedef float floatx4 __attribute__((ext_vector_type(4)));

static constexpr float SCALE = 0.125f;                    // 1/sqrt(64)
static constexpr float LN3 = 1.0986122886681098f;
static constexpr float INV_SQRT_2PI = 0.3989422804014327f;
static constexpr size_t NMAT = (size_t)BB * HH * LL * LL;
static constexpr size_t SERIES_BASE = (size_t)BB * LL * HH * EE;
static constexpr size_t PRIOR_BASE = SERIES_BASE + NMAT;
static constexpr size_t SIG_BASE = PRIOR_BASE + NMAT;

// Fused kernel: two-pass normalized attention (proven numerics) restructured
// for concurrency: 512 threads / 8 waves per block, TN=128 j-tiles.
// QK: wave = (row-group w&3, j-half w>>2). PV: wave = (row-group, e-half).
// 16 waves/CU (2 blocks x 8 waves), ~34 tile-iterations per block.
__global__ __launch_bounds__(512, 4)
void anomaly_attn(const float* __restrict__ qg,
                  const float* __restrict__ kg,
                  const float* __restrict__ vg,
                  const float* __restrict__ sgg,
                  float* __restrict__ out) {
  __shared__ __attribute__((aligned(16))) _Float16 Qh[TM * SH];    //  9216 B
  __shared__ __attribute__((aligned(16))) _Float16 Kh[TN * SH];    // 18432 B
  __shared__ __attribute__((aligned(16))) _Float16 Vt[EE * SH2];   // 17408 B (transposed [e][j])
  __shared__ __attribute__((aligned(16))) _Float16 Ph[TM * SH2];   // 17408 B
  __shared__ float s_red[2][TM];
  __shared__ float s_sigv[TM], s_pinv[TM], s_c2[TM];

  const int t = threadIdx.x;
  const int lane = t & 63;
  const int w = t >> 6;          // 0..7
  const int rg = w & 3;          // row group: rows rg*16..rg*16+15
  const int jh = w >> 2;         // j-half (QK) / e-half (PV)
  const int quad = lane >> 4;
  const int l15 = lane & 15;
  const int bh = blockIdx.y;
  const int b = bh >> 3, h = bh & 7;
  const float4* q4 = (const float4*)qg;
  const float4* k4 = (const float4*)kg;
  const float4* v4 = (const float4*)vg;

  for (int half = 0; half < 2; ++half) {
    const int rt = half ? (31 - (int)blockIdx.x) : (int)blockIdx.x;
    const int i0 = rt * TM;
    const int nt64 = rt + 1;            // causal 64-col tiles
    const int nt = (nt64 + 1) >> 1;     // 128-col tiles (last may be half-masked)
    __syncthreads();                    // protect LDS/s_* from previous half

    // ---- stage Q (64x64 fp32 -> fp16 LDS): 1024 float4 units / 512 thr ----
#pragma unroll
    for (int it = 0; it < 2; ++it) {
      int idx = t + 512 * it;
      int r = idx >> 4, c = idx & 15;
      float4 qv = q4[(((size_t)b * LL + i0 + r) * HH + h) * 16 + c];
      half4v hq = {(_Float16)qv.x, (_Float16)qv.y, (_Float16)qv.z, (_Float16)qv.w};
      *(half4v*)&Qh[r * SH + c * 4] = hq;
    }
    // ---- per-row sigma transform (for prior/sig tail) ----
    if (t < TM) {
      float sg = sgg[((size_t)b * LL + (i0 + t)) * HH + h];
      float sd = 1.0f / (1.0f + __expf(-5.0f * sg)) + 1e-5f;
      float sv = expm1f(sd * LN3);
      s_sigv[t] = sv;
      s_pinv[t] = INV_SQRT_2PI / sv;
      s_c2[t] = 0.5f / (sv * sv);
    }

    // ================= pass 1: row sums of exp(scale*s) =================
    float lsum[4] = {0.f, 0.f, 0.f, 0.f};
    for (int jt = 0; jt < nt; ++jt) {
      const int j0 = jt * TN;
      __syncthreads();               // prev iter's Kh readers done
      // stage K: 128 rows x 16 float4 = 2048 units / 512 thr
#pragma unroll
      for (int it = 0; it < 4; ++it) {
        int idx = t + 512 * it;
        int r = idx >> 4, c = idx & 15;
        float4 kv = k4[(((size_t)b * LL + j0 + r) * HH + h) * 16 + c];
        half4v hk = {(_Float16)kv.x, (_Float16)kv.y, (_Float16)kv.z, (_Float16)kv.w};
        *(half4v*)&Kh[r * SH + c * 4] = hk;
      }
      __syncthreads();
      floatx4 acc[4] = {{0.f, 0.f, 0.f, 0.f}, {0.f, 0.f, 0.f, 0.f},
                        {0.f, 0.f, 0.f, 0.f}, {0.f, 0.f, 0.f, 0.f}};
#pragma unroll
      for (int ks = 0; ks < 2; ++ks) {
        half8v a = *(half8v*)&Qh[(rg * 16 + l15) * SH + ks * 32 + quad * 8];
#pragma unroll
        for (int f = 0; f < 4; ++f) {
          half8v bf = *(half8v*)&Kh[(jh * 64 + f * 16 + l15) * SH + ks * 32 + quad * 8];
          acc[f] = __builtin_amdgcn_mfma_f32_16x16x32_f16(a, bf, acc[f], 0, 0, 0);
        }
      }
#pragma unroll
      for (int f = 0; f < 4; ++f) {
        int j = j0 + jh * 64 + f * 16 + l15;
#pragma unroll
        for (int r = 0; r < 4; ++r) {
          int i = i0 + rg * 16 + quad * 4 + r;
          lsum[r] += (j <= i) ? __expf(acc[f][r] * SCALE) : 0.f;
        }
      }
    }
    // reduce across l15 within quad, then combine the two j-half waves via LDS
#pragma unroll
    for (int r = 0; r < 4; ++r) {
      lsum[r] += __shfl_xor(lsum[r], 1);
      lsum[r] += __shfl_xor(lsum[r], 2);
      lsum[r] += __shfl_xor(lsum[r], 4);
      lsum[r] += __shfl_xor(lsum[r], 8);
    }
    if (l15 == 0) {
#pragma unroll
      for (int r = 0; r < 4; ++r) s_red[jh][rg * 16 + quad * 4 + r] = lsum[r];
    }
    __syncthreads();
    float linv[4];
#pragma unroll
    for (int r = 0; r < 4; ++r) {
      int row = rg * 16 + quad * 4 + r;
      linv[r] = 1.0f / (s_red[0][row] + s_red[1][row]);
    }

    // ================= pass 2: series + PV =================
    floatx4 Oacc[2] = {{0.f, 0.f, 0.f, 0.f}, {0.f, 0.f, 0.f, 0.f}};
    for (int jt = 0; jt < nt; ++jt) {
      const int j0 = jt * TN;
      __syncthreads();               // prev iter's Kh/Vt/Ph readers done
      // stage K (128 rows)
#pragma unroll
      for (int it = 0; it < 4; ++it) {
        int idx = t + 512 * it;
        int r = idx >> 4, c = idx & 15;
        float4 kv = k4[(((size_t)b * LL + j0 + r) * HH + h) * 16 + c];
        half4v hk = {(_Float16)kv.x, (_Float16)kv.y, (_Float16)kv.z, (_Float16)kv.w};
        *(half4v*)&Kh[r * SH + c * 4] = hk;
      }
      // stage V transposed: thread (tx=e4-group 0..15, ty=j4-group 0..31)
      {
        const int tx = t & 15, ty = t >> 4;
        float4 vv[4];
#pragma unroll
        for (int rr = 0; rr < 4; ++rr)
          vv[rr] = v4[(((size_t)b * LL + j0 + ty * 4 + rr) * HH + h) * 16 + tx];
#pragma unroll
        for (int c = 0; c < 4; ++c) {
          float e0 = c == 0 ? vv[0].x : c == 1 ? vv[0].y : c == 2 ? vv[0].z : vv[0].w;
          float e1 = c == 0 ? vv[1].x : c == 1 ? vv[1].y : c == 2 ? vv[1].z : vv[1].w;
          float e2 = c == 0 ? vv[2].x : c == 1 ? vv[2].y : c == 2 ? vv[2].z : vv[2].w;
          float e3 = c == 0 ? vv[3].x : c == 1 ? vv[3].y : c == 2 ? vv[3].z : vv[3].w;
          half4v hv = {(_Float16)e0, (_Float16)e1, (_Float16)e2, (_Float16)e3};
          *(half4v*)&Vt[(tx * 4 + c) * SH2 + ty * 4] = hv;
        }
      }
      __syncthreads();
      // QK
      floatx4 acc[4] = {{0.f, 0.f, 0.f, 0.f}, {0.f, 0.f, 0.f, 0.f},
                        {0.f, 0.f, 0.f, 0.f}, {0.f, 0.f, 0.f, 0.f}};
#pragma unroll
      for (int ks = 0; ks < 2; ++ks) {
        half8v a = *(half8v*)&Qh[(rg * 16 + l15) * SH + ks * 32 + quad * 8];
#pragma unroll
        for (int f = 0; f < 4; ++f) {
          half8v bf = *(half8v*)&Kh[(jh * 64 + f * 16 + l15) * SH + ks * 32 + quad * 8];
          acc[f] = __builtin_amdgcn_mfma_f32_16x16x32_f16(a, bf, acc[f], 0, 0, 0);
        }
      }
      // P normalized -> Ph (this wave's 16x64 sub-block)
#pragma unroll
      for (int f = 0; f < 4; ++f) {
        int j = j0 + jh * 64 + f * 16 + l15;
#pragma unroll
        for (int r = 0; r < 4; ++r) {
          int i = i0 + rg * 16 + quad * 4 + r;
          float p = (j <= i) ? __expf(acc[f][r] * SCALE) * linv[r] : 0.f;
          Ph[(rg * 16 + quad * 4 + r) * SH2 + jh * 64 + f * 16 + l15] = (_Float16)p;
        }
      }
      // wave-local series readback (region this wave just wrote) -> NT stores
#pragma unroll
      for (int rnd = 0; rnd < 2; ++rnd) {
        int row = rg * 16 + rnd * 8 + (lane >> 3);
        int c8 = lane & 7;
        half8v p = *(half8v*)&Ph[row * SH2 + jh * 64 + c8 * 8];
        floatx4 lo = {(float)p[0], (float)p[1], (float)p[2], (float)p[3]};
        floatx4 hi = {(float)p[4], (float)p[5], (float)p[6], (float)p[7]};
        size_t off = SERIES_BASE + ((size_t)bh * LL + i0 + row) * LL + j0 + jh * 64 + c8 * 8;
        __builtin_nontemporal_store(lo, (floatx4*)&out[off]);
        __builtin_nontemporal_store(hi, (floatx4*)&out[off + 4]);
      }
      __syncthreads();               // full-width Ph visible for PV
      // PV: wave = (row-group rg, e-half jh); K-dim = 128 j-cols
#pragma unroll
      for (int ks = 0; ks < 4; ++ks) {
        half8v a = *(half8v*)&Ph[(rg * 16 + l15) * SH2 + ks * 32 + quad * 8];
#pragma unroll
        for (int f2 = 0; f2 < 2; ++f2) {
          half8v bv = *(half8v*)&Vt[(jh * 32 + f2 * 16 + l15) * SH2 + ks * 32 + quad * 8];
          Oacc[f2] = __builtin_amdgcn_mfma_f32_16x16x32_f16(a, bv, Oacc[f2], 0, 0, 0);
        }
      }
    }
    // ---- V output (already normalized) ----
#pragma unroll
    for (int f2 = 0; f2 < 2; ++f2) {
#pragma unroll
      for (int r = 0; r < 4; ++r) {
        int i = i0 + rg * 16 + quad * 4 + r;
        int e = jh * 32 + f2 * 16 + l15;
        out[(((size_t)b * LL + i) * HH + h) * EE + e] = Oacc[f2][r];
      }
    }
    // ---- prior + sig full rows (NT: never re-read) ----
    for (int idx = t; idx < TM * 512; idx += 512) {
      int rr = idx >> 9, jq = idx & 511;
      float iv = s_pinv[rr], c2 = s_c2[rr], sv = s_sigv[rr];
      float fi = (float)(i0 + rr);
      float d0 = fi - (float)(jq * 4);
      float d1 = d0 - 1.0f, d2 = d0 - 2.0f, d3 = d0 - 3.0f;
      floatx4 pr;
      pr.x = iv * __expf(-d0 * d0 * c2);
      pr.y = iv * __expf(-d1 * d1 * c2);
      pr.z = iv * __expf(-d2 * d2 * c2);
      pr.w = iv * __expf(-d3 * d3 * c2);
      size_t off = ((size_t)bh * LL + (i0 + rr)) * LL + jq * 4;
      __builtin_nontemporal_store(pr, (floatx4*)&out[PRIOR_BASE + off]);
      floatx4 sg4 = {sv, sv, sv, sv};
      __builtin_nontemporal_store(sg4, (floatx4*)&out[SIG_BASE + off]);
    }
    // ---- series zero-fill beyond the 128-tile causal region ----
    {
      int jz = nt * TN;
      int nz4 = (LL - jz) >> 2;
      if (nz4 > 0) {
        const floatx4 z = {0.f, 0.f, 0.f, 0.f};
        for (int rr = 0; rr < TM; ++rr) {
          float* rowp = &out[SERIES_BASE + ((size_t)bh * LL + (i0 + rr)) * LL + jz];
          for (int c = t; c < nz4; c += 512) {
            __builtin_nontemporal_store(z, (floatx4*)&rowp[c * 4]);
          }
        }
      }
    }
  }
}

extern "C" void kernel_launch(void* const* d_in, const int* in_sizes, int n_in,
                              void* d_out, int out_size, void* d_ws, size_t ws_size,
                              hipStream_t stream) {
  const float* q = (const float*)d_in[0];
  const float* k = (const float*)d_in[1];
  const float* v = (const float*)d_in[2];
  const float* sg = (const float*)d_in[3];
  float* out = (float*)d_out;
  dim3 grid(LL / TM / 2, BB * HH);  // 16 x 32 = 512 blocks x 512 thr, strip-paired
  anomaly_attn<<<grid, 512, 0, stream>>>(q, k, v, sg, out);
}